// Round 1
// baseline (353.926 us; speedup 1.0000x reference)
//
#include <hip/hip_runtime.h>
#include <math.h>

// Problem constants
#define LQ 1024
#define EQ 512
#define BQ 32
#define MQ 64

static constexpr int BCHUNK = LQ * EQ;   // 524288 floats per b-slice of d_out
static constexpr int XOFF   = 262144;    // xg overlay offset inside each b-slice
// d_out overlay (per b-slice of 524288 floats):
//   O_A[b][c][i]  c in [0,128)   at  b*BCHUNK + c*512 + i
//   O_B[b][c][i]  c in [0,128)   at  b*BCHUNK + (128+c)*512 + i
//   X  [b][h][m][ri]             at  b*BCHUNK + XOFF + (h*64+m)*2 + ri
// Final kernel overwrites everything with y[b][l][i].

// ---------------- kernel 0: trig tables ----------------
// T1[l][m][2] = (cos th, -sin th), th = 2*pi*l*m/L       (for forward DFT)
// Bas[l][c]:  c=2m   -> ((m==0)?1:2)/L * cos th
//             c=2m+1 -> (m==0)? 0 : -2/L * sin th        (irfft, Im X0 ignored)
__global__ __launch_bounds__(256) void k_trig(float* __restrict__ T1,
                                              float* __restrict__ Bas) {
    int idx = blockIdx.x * 256 + threadIdx.x;   // 0..65535 = l*64+m
    int l = idx >> 6, m = idx & 63;
    int tt = (l * m) & (LQ - 1);
    float ang = (float)tt * 6.135923151542565e-03f;  // 2*pi/1024
    float s, c;
    sincosf(ang, &s, &c);
    T1[idx * 2 + 0] = c;
    T1[idx * 2 + 1] = -s;
    float coef = (m == 0 ? 1.0f : 2.0f) * (1.0f / (float)LQ);
    Bas[l * 128 + 2 * m + 0] = coef * c;
    Bas[l * 128 + 2 * m + 1] = (m == 0) ? 0.0f : (-2.0f / (float)LQ) * s;
}

// ---------------- kernel 1: truncated DFT ----------------
// X[b][h][m][ri] = sum_l q[b][l][h] * (cos, -sin)
// grid 256 = b(32) x htile(8); block 256 = hh(32 h-pairs) x g(8 mode-groups of 8)
__global__ __launch_bounds__(256) void k_dft(const float* __restrict__ q,
                                             const float* __restrict__ T1,
                                             float* __restrict__ dout) {
    __shared__ float qs[64 * 64];     // [l'][h']  16KB
    __shared__ float ts[64 * 128];    // [l'][m*2+ri] 32KB
    const int t  = threadIdx.x;
    const int b  = blockIdx.x >> 3;
    const int h0 = (blockIdx.x & 7) << 6;
    const int hh = t & 31;            // h-pair index
    const int g  = t >> 5;            // mode group: modes [8g, 8g+8)
    float accr[2][8] = {};
    float acci[2][8] = {};
    const float* qb = q + (size_t)b * (LQ * EQ) + h0;

    for (int lt = 0; lt < 16; ++lt) {
        const int l0 = lt << 6;
        __syncthreads();
#pragma unroll
        for (int k = 0; k < 16; ++k) {          // stage q tile 64l x 64h
            int idx = k * 256 + t;
            int lp = idx >> 6, hp = idx & 63;
            qs[idx] = qb[(size_t)(l0 + lp) * EQ + hp];
        }
#pragma unroll
        for (int k = 0; k < 32; ++k) {          // stage trig tile 64l x 128
            int idx = k * 256 + t;
            ts[idx] = T1[l0 * 128 + idx];
        }
        __syncthreads();
#pragma unroll 4
        for (int lp = 0; lp < 64; ++lp) {
            float2 qq = *(const float2*)&qs[lp * 64 + 2 * hh];
            const float4* tr = (const float4*)&ts[lp * 128 + g * 16];
#pragma unroll
            for (int j = 0; j < 4; ++j) {       // modes 8g+2j, 8g+2j+1
                float4 tv = tr[j];
                accr[0][2 * j]     += qq.x * tv.x;
                acci[0][2 * j]     += qq.x * tv.y;
                accr[0][2 * j + 1] += qq.x * tv.z;
                acci[0][2 * j + 1] += qq.x * tv.w;
                accr[1][2 * j]     += qq.y * tv.x;
                acci[1][2 * j]     += qq.y * tv.y;
                accr[1][2 * j + 1] += qq.y * tv.z;
                acci[1][2 * j + 1] += qq.y * tv.w;
            }
        }
    }
    float* xb = dout + (size_t)b * BCHUNK + XOFF;
#pragma unroll
    for (int hp = 0; hp < 2; ++hp) {
        int h = h0 + 2 * hh + hp;
#pragma unroll
        for (int mm = 0; mm < 8; ++mm) {
            int m = g * 8 + mm;
            float2 v = make_float2(accr[hp][mm], acci[hp][mm]);
            *(float2*)&xb[(size_t)(h * 64 + m) * 2] = v;
        }
    }
}

// ---------------- kernel 2: per-mode complex GEMM ----------------
// O[b][2m+ri][i] (+ h-split partials) = sum_h X[b][h][m] * W[h][i][m]
// grid 256: hs(2) x mg(4: 16 modes) x ig(32: 16 i's). block 256 = ti(16) x tm(16)
__global__ __launch_bounds__(256) void k_modes(const float* __restrict__ wreal,
                                               const float* __restrict__ wimag,
                                               float* __restrict__ dout) {
    __shared__ float Ws0[8 * 256];   // [h'][i'][m']  8KB
    __shared__ float Ws1[8 * 256];
    __shared__ float Xs[32 * 256];   // [b][h'][m'][ri] 32KB
    const int t  = threadIdx.x;
    const int bi = blockIdx.x;
    const int hs = bi & 1;
    const int mg = (bi >> 1) & 3;
    const int ig = bi >> 3;
    const int i0 = ig * 16, m0 = mg * 16, hb = hs * 256;
    const int tm = t & 15, ti = t >> 4;
    float ar[32] = {}, ai[32] = {};

    for (int hc = 0; hc < 32; ++hc) {
        const int h1 = hb + hc * 8;
        __syncthreads();
        // stage W tiles: 2048 floats each, float2 per thread x4
#pragma unroll
        for (int k = 0; k < 4; ++k) {
            int p = t + 256 * k;
            int e = 2 * p;                       // [hp][ip][mloc] flat
            int mloc = e & 15, ip = (e >> 4) & 15, hp = e >> 8;
            size_t g = ((size_t)(h1 + hp) * EQ + (i0 + ip)) * 64 + (m0 + mloc);
            *(float2*)&Ws0[e] = *(const float2*)&wreal[g];
            *(float2*)&Ws1[e] = *(const float2*)&wimag[g];
        }
        // stage X tile: 8192 floats, float2 per thread x16
#pragma unroll
        for (int k = 0; k < 16; ++k) {
            int p = t + 256 * k;
            int e = 2 * p;                       // [b][h'][m'][ri] flat
            int bb = e >> 8;
            int rest = e & 255;
            int hp = rest >> 5;
            int mp = (rest & 31) >> 1;
            size_t g = (size_t)bb * BCHUNK + XOFF +
                       ((size_t)(h1 + hp) * 64 + (m0 + mp)) * 2;
            *(float2*)&Xs[e] = *(const float2*)&dout[g];
        }
        __syncthreads();
#pragma unroll
        for (int hp = 0; hp < 8; ++hp) {
            float w_r = Ws0[hp * 256 + t - (t & ~255)];  // = Ws0[hp*256 + ti*16 + tm]
            float w_i = Ws1[hp * 256 + ti * 16 + tm];
            w_r = Ws0[hp * 256 + ti * 16 + tm];
#pragma unroll
            for (int bb = 0; bb < 32; ++bb) {
                float2 x = *(const float2*)&Xs[bb * 256 + hp * 32 + tm * 2];
                ar[bb] += x.x * w_r;
                ar[bb] -= x.y * w_i;
                ai[bb] += x.x * w_i;
                ai[bb] += x.y * w_r;
            }
        }
    }
    const int crow = 2 * (m0 + tm) + hs * 128;
#pragma unroll
    for (int bb = 0; bb < 32; ++bb) {
        float* ob = dout + (size_t)bb * BCHUNK;
        ob[(size_t)crow * EQ + i0 + ti]       = ar[bb];
        ob[(size_t)(crow + 1) * EQ + i0 + ti] = ai[bb];
    }
}

// ---------------- kernel 2b: reduce h-split partials: O_A += O_B ----------------
__global__ __launch_bounds__(256) void k_reduce(float* __restrict__ dout) {
    int idx = blockIdx.x * 256 + threadIdx.x;   // float4 index, 524288 total
    int b = idx >> 14;                          // 16384 float4 per b (= O_A)
    int r = idx & 16383;
    float* base = dout + (size_t)b * BCHUNK;
    float4 va = ((const float4*)base)[r];
    float4 vb = ((const float4*)(base + 65536))[r];
    va.x += vb.x; va.y += vb.y; va.z += vb.z; va.w += vb.w;
    ((float4*)base)[r] = va;
}

// ---------------- kernel 3: truncated irfft ----------------
// y[b][l][i] = sum_c Bas[l][c] * O[b][c][i]
// grid 256 = b(32) x itile(8: 64 i's); block 256 = lg(16: 4 l's) x ti2(16: 4 i's)
__global__ __launch_bounds__(256) void k_inv(const float* __restrict__ Bas,
                                             float* __restrict__ dout) {
    __shared__ float Os[128 * 64];    // [c][ii] 32KB — staged BEFORE any write
    __shared__ float Bs[64 * 132];    // [l'][c] padded 33KB
    const int t  = threadIdx.x;
    const int b  = blockIdx.x >> 3;
    const int i0 = (blockIdx.x & 7) << 6;
    float* yb = dout + (size_t)b * BCHUNK;
#pragma unroll
    for (int k = 0; k < 32; ++k) {              // stage O (own read region)
        int e = k * 256 + t;
        int c = e >> 6, ii = e & 63;
        Os[e] = yb[(size_t)c * EQ + i0 + ii];
    }
    __syncthreads();
    const int lg = t >> 4, ti2 = t & 15;
    for (int lt = 0; lt < 16; ++lt) {
        const int l0 = lt << 6;
        if (lt) __syncthreads();
#pragma unroll
        for (int k = 0; k < 32; ++k) {          // stage Bas tile (padded rows)
            int e = k * 256 + t;
            int lp = e >> 7, c = e & 127;
            Bs[lp * 132 + c] = Bas[(size_t)(l0 + lp) * 128 + c];
        }
        __syncthreads();
        float4 acc[4] = {};
#pragma unroll 4
        for (int c = 0; c < 128; ++c) {
            float4 ov = *(const float4*)&Os[c * 64 + ti2 * 4];
#pragma unroll
            for (int j = 0; j < 4; ++j) {
                float bv = Bs[(lg * 4 + j) * 132 + c];
                acc[j].x += bv * ov.x;
                acc[j].y += bv * ov.y;
                acc[j].z += bv * ov.z;
                acc[j].w += bv * ov.w;
            }
        }
#pragma unroll
        for (int j = 0; j < 4; ++j) {
            int l = l0 + lg * 4 + j;
            *(float4*)&yb[(size_t)l * EQ + i0 + ti2 * 4] = acc[j];
        }
    }
}

extern "C" void kernel_launch(void* const* d_in, const int* in_sizes, int n_in,
                              void* d_out, int out_size, void* d_ws, size_t ws_size,
                              hipStream_t stream) {
    const float* q  = (const float*)d_in[0];
    const float* wr = (const float*)d_in[1];
    const float* wi = (const float*)d_in[2];
    float* out = (float*)d_out;
    float* T1  = (float*)d_ws;          // 131072 floats
    float* Bas = T1 + 131072;           // 131072 floats  (needs 1 MB of ws)

    hipLaunchKernelGGL(k_trig,   dim3(256),  dim3(256), 0, stream, T1, Bas);
    hipLaunchKernelGGL(k_dft,    dim3(256),  dim3(256), 0, stream, q, T1, out);
    hipLaunchKernelGGL(k_modes,  dim3(256),  dim3(256), 0, stream, wr, wi, out);
    hipLaunchKernelGGL(k_reduce, dim3(2048), dim3(256), 0, stream, out);
    hipLaunchKernelGGL(k_inv,    dim3(256),  dim3(256), 0, stream, Bas, out);
}

// Round 2
// 301.581 us; speedup vs baseline: 1.1736x; 1.1736x over previous
//
#include <hip/hip_runtime.h>
#include <math.h>

// Problem constants
#define LQ 1024
#define EQ 512
#define BQ 32
#define MQ 64

static constexpr int BCHUNK = LQ * EQ;   // 524288 floats per b-slice of d_out
static constexpr int XO2    = 327680;    // X overlay offset inside each b-slice
// d_out overlay (per b-slice of 524288 floats):
//   O_final[b][c][i]   c in [0,128)  at  b*BCHUNK + c*512 + i            [0,65536)
//   O_part[p][b][c][i] p in [0,4)    at  b*BCHUNK + (1+p)*65536 + c*512+i [65536,327680)
//   X[b][h][m][ri]                   at  b*BCHUNK + XO2 + (h*64+m)*2      [327680,393216)
// Final kernel overwrites everything with y[b][l][i].

// ---------------- kernel 0: trig tables ----------------
__global__ __launch_bounds__(256) void k_trig(float* __restrict__ T1,
                                              float* __restrict__ Bas) {
    int idx = blockIdx.x * 256 + threadIdx.x;   // 0..65535 = l*64+m
    int l = idx >> 6, m = idx & 63;
    int tt = (l * m) & (LQ - 1);
    float ang = (float)tt * 6.135923151542565e-03f;  // 2*pi/1024
    float s, c;
    sincosf(ang, &s, &c);
    T1[idx * 2 + 0] = c;
    T1[idx * 2 + 1] = -s;
    float coef = (m == 0 ? 1.0f : 2.0f) * (1.0f / (float)LQ);
    Bas[l * 128 + 2 * m + 0] = coef * c;
    Bas[l * 128 + 2 * m + 1] = (m == 0) ? 0.0f : (-2.0f / (float)LQ) * s;
}

// ---------------- kernel 1: truncated DFT ----------------
// X[b][h][m][ri] = sum_l q[b][l][h] * (cos, -sin)
__global__ __launch_bounds__(256) void k_dft(const float* __restrict__ q,
                                             const float* __restrict__ T1,
                                             float* __restrict__ dout) {
    __shared__ float qs[64 * 64];     // [l'][h']  16KB
    __shared__ float ts[64 * 128];    // [l'][m*2+ri] 32KB
    const int t  = threadIdx.x;
    const int b  = blockIdx.x >> 3;
    const int h0 = (blockIdx.x & 7) << 6;
    const int hh = t & 31;            // h-pair index
    const int g  = t >> 5;            // mode group: modes [8g, 8g+8)
    float accr[2][8] = {};
    float acci[2][8] = {};
    const float* qb = q + (size_t)b * (LQ * EQ) + h0;

    for (int lt = 0; lt < 16; ++lt) {
        const int l0 = lt << 6;
        __syncthreads();
#pragma unroll
        for (int k = 0; k < 16; ++k) {          // stage q tile 64l x 64h
            int idx = k * 256 + t;
            int lp = idx >> 6, hp = idx & 63;
            qs[idx] = qb[(size_t)(l0 + lp) * EQ + hp];
        }
#pragma unroll
        for (int k = 0; k < 32; ++k) {          // stage trig tile 64l x 128
            int idx = k * 256 + t;
            ts[idx] = T1[l0 * 128 + idx];
        }
        __syncthreads();
#pragma unroll 4
        for (int lp = 0; lp < 64; ++lp) {
            float2 qq = *(const float2*)&qs[lp * 64 + 2 * hh];
            const float4* tr = (const float4*)&ts[lp * 128 + g * 16];
#pragma unroll
            for (int j = 0; j < 4; ++j) {       // modes 8g+2j, 8g+2j+1
                float4 tv = tr[j];
                accr[0][2 * j]     += qq.x * tv.x;
                acci[0][2 * j]     += qq.x * tv.y;
                accr[0][2 * j + 1] += qq.x * tv.z;
                acci[0][2 * j + 1] += qq.x * tv.w;
                accr[1][2 * j]     += qq.y * tv.x;
                acci[1][2 * j]     += qq.y * tv.y;
                accr[1][2 * j + 1] += qq.y * tv.z;
                acci[1][2 * j + 1] += qq.y * tv.w;
            }
        }
    }
    float* xb = dout + (size_t)b * BCHUNK + XO2;
#pragma unroll
    for (int hp = 0; hp < 2; ++hp) {
        int h = h0 + 2 * hh + hp;
#pragma unroll
        for (int mm = 0; mm < 8; ++mm) {
            int m = g * 8 + mm;
            float2 v = make_float2(accr[hp][mm], acci[hp][mm]);
            *(float2*)&xb[(size_t)(h * 64 + m) * 2] = v;
        }
    }
}

// ---------------- kernel 2: per-mode complex GEMM, v2 ----------------
// O_part[hs][b][2m+ri][i] = sum_{h in hs-range} X[b][h][m] * W[h][i][m]
// grid 256 = hs(4) x it(64, 8 i's each). block 512 = m(64 lanes) x slot(8)
// slot = is(2) x bs(4); thread: 4 i's (is*4+ii), 8 b's (bs*8+bb), 1 m.
// W read directly from global (coalesced over m-lanes, used once).
__global__ __launch_bounds__(512) void k_modes2(const float* __restrict__ wreal,
                                                const float* __restrict__ wimag,
                                                float* __restrict__ dout) {
    __shared__ float Xs[4 * 32 * 128];      // [h'][b][m*2+ri] 64KB
    __shared__ float Ot[64 * 66];           // epilogue transpose 16.9KB
    const int t    = threadIdx.x;
    const int m    = t & 63;
    const int slot = t >> 6;
    const int is   = slot & 1;
    const int bs   = slot >> 1;
    const int bi   = blockIdx.x;
    const int hs   = bi >> 6;
    const int it   = bi & 63;
    const int i0   = it * 8;
    const int iTh  = i0 + is * 4;
    float ar[4][8] = {}, ai[4][8] = {};

    for (int c = 0; c < 32; ++c) {
        const int h0 = hs * 128 + c * 4;
        // W register prefetch for this 4-h chunk (in flight during staging)
        float wr[4][4], wi[4][4];
#pragma unroll
        for (int hp = 0; hp < 4; ++hp)
#pragma unroll
            for (int ii = 0; ii < 4; ++ii) {
                size_t g = ((size_t)(h0 + hp) * EQ + (iTh + ii)) * 64 + m;
                wr[hp][ii] = wreal[g];
                wi[hp][ii] = wimag[g];
            }
        __syncthreads();                     // previous chunk's Xs consumed
#pragma unroll
        for (int k = 0; k < 16; ++k) {       // stage X chunk: [4h][32b][64m] cplx
            int e  = k * 512 + t;            // float2 index
            int b  = e >> 8, hm = e & 255;
            int hp = hm >> 6, mm = hm & 63;
            float2 v = *(const float2*)&dout[(size_t)b * BCHUNK + XO2 +
                                             (size_t)((h0 + hp) * 64 + mm) * 2];
            *(float2*)&Xs[hp * 4096 + b * 128 + mm * 2] = v;
        }
        __syncthreads();
#pragma unroll
        for (int hp = 0; hp < 4; ++hp) {
            float2 x[8];
#pragma unroll
            for (int bb = 0; bb < 8; ++bb)
                x[bb] = *(const float2*)&Xs[hp * 4096 + (bs * 8 + bb) * 128 + m * 2];
#pragma unroll
            for (int ii = 0; ii < 4; ++ii) {
                float wrv = wr[hp][ii], wiv = wi[hp][ii];
#pragma unroll
                for (int bb = 0; bb < 8; ++bb) {
                    ar[ii][bb] += x[bb].x * wrv;
                    ar[ii][bb] -= x[bb].y * wiv;
                    ai[ii][bb] += x[bb].x * wiv;
                    ai[ii][bb] += x[bb].y * wrv;
                }
            }
        }
    }
    // epilogue: LDS transpose so stores are 32B-coalesced rows
    for (int bb = 0; bb < 8; ++bb) {
        __syncthreads();
#pragma unroll
        for (int ii = 0; ii < 4; ++ii) {
            float2 v = make_float2(ar[ii][bb], ai[ii][bb]);
            *(float2*)&Ot[m * 66 + (is * 4 + ii) * 8 + bs * 2] = v;
        }
        __syncthreads();
#pragma unroll
        for (int k = 0; k < 8; ++k) {
            int e    = k * 512 + t;          // [bs2(4)][c(128)][iLoc(8)]
            int iLoc = e & 7, cc = (e >> 3) & 127, bs2 = e >> 10;
            float val = Ot[(cc >> 1) * 66 + iLoc * 8 + bs2 * 2 + (cc & 1)];
            int b = bs2 * 8 + bb;
            dout[(size_t)b * BCHUNK + (size_t)(1 + hs) * 65536 +
                 (size_t)cc * EQ + i0 + iLoc] = val;
        }
    }
}

// ---------------- kernel 2b: sum the 4 h-split partials into O_final ----------------
__global__ __launch_bounds__(256) void k_reduce2(float* __restrict__ dout) {
    int idx = blockIdx.x * 256 + threadIdx.x;   // float4 index, 524288 total
    int b = idx >> 14;                          // 16384 float4 per b
    int r = idx & 16383;
    float* base = dout + (size_t)b * BCHUNK;
    float4 s0 = ((const float4*)(base + 65536))[r];
    float4 s1 = ((const float4*)(base + 2 * 65536))[r];
    float4 s2 = ((const float4*)(base + 3 * 65536))[r];
    float4 s3 = ((const float4*)(base + 4 * 65536))[r];
    float4 o;
    o.x = (s0.x + s1.x) + (s2.x + s3.x);
    o.y = (s0.y + s1.y) + (s2.y + s3.y);
    o.z = (s0.z + s1.z) + (s2.z + s3.z);
    o.w = (s0.w + s1.w) + (s2.w + s3.w);
    ((float4*)base)[r] = o;
}

// ---------------- kernel 3: truncated irfft ----------------
__global__ __launch_bounds__(256) void k_inv(const float* __restrict__ Bas,
                                             float* __restrict__ dout) {
    __shared__ float Os[128 * 64];    // [c][ii] 32KB — staged BEFORE any write
    __shared__ float Bs[64 * 132];    // [l'][c] padded 33KB
    const int t  = threadIdx.x;
    const int b  = blockIdx.x >> 3;
    const int i0 = (blockIdx.x & 7) << 6;
    float* yb = dout + (size_t)b * BCHUNK;
#pragma unroll
    for (int k = 0; k < 32; ++k) {              // stage O (own read region)
        int e = k * 256 + t;
        int c = e >> 6, ii = e & 63;
        Os[e] = yb[(size_t)c * EQ + i0 + ii];
    }
    __syncthreads();
    const int lg = t >> 4, ti2 = t & 15;
    for (int lt = 0; lt < 16; ++lt) {
        const int l0 = lt << 6;
        if (lt) __syncthreads();
#pragma unroll
        for (int k = 0; k < 32; ++k) {          // stage Bas tile (padded rows)
            int e = k * 256 + t;
            int lp = e >> 7, c = e & 127;
            Bs[lp * 132 + c] = Bas[(size_t)(l0 + lp) * 128 + c];
        }
        __syncthreads();
        float4 acc[4] = {};
#pragma unroll 4
        for (int c = 0; c < 128; ++c) {
            float4 ov = *(const float4*)&Os[c * 64 + ti2 * 4];
#pragma unroll
            for (int j = 0; j < 4; ++j) {
                float bv = Bs[(lg * 4 + j) * 132 + c];
                acc[j].x += bv * ov.x;
                acc[j].y += bv * ov.y;
                acc[j].z += bv * ov.z;
                acc[j].w += bv * ov.w;
            }
        }
#pragma unroll
        for (int j = 0; j < 4; ++j) {
            int l = l0 + lg * 4 + j;
            *(float4*)&yb[(size_t)l * EQ + i0 + ti2 * 4] = acc[j];
        }
    }
}

extern "C" void kernel_launch(void* const* d_in, const int* in_sizes, int n_in,
                              void* d_out, int out_size, void* d_ws, size_t ws_size,
                              hipStream_t stream) {
    const float* q  = (const float*)d_in[0];
    const float* wr = (const float*)d_in[1];
    const float* wi = (const float*)d_in[2];
    float* out = (float*)d_out;
    float* T1  = (float*)d_ws;          // 131072 floats
    float* Bas = T1 + 131072;           // 131072 floats  (1 MB of ws total)

    hipLaunchKernelGGL(k_trig,    dim3(256),  dim3(256), 0, stream, T1, Bas);
    hipLaunchKernelGGL(k_dft,     dim3(256),  dim3(256), 0, stream, q, T1, out);
    hipLaunchKernelGGL(k_modes2,  dim3(256),  dim3(512), 0, stream, wr, wi, out);
    hipLaunchKernelGGL(k_reduce2, dim3(2048), dim3(256), 0, stream, out);
    hipLaunchKernelGGL(k_inv,     dim3(256),  dim3(256), 0, stream, Bas, out);
}

// Round 3
// 283.690 us; speedup vs baseline: 1.2476x; 1.0631x over previous
//
#include <hip/hip_runtime.h>
#include <math.h>

// Problem constants
#define LQ 1024
#define EQ 512
#define BQ 32
#define MQ 64

static constexpr int BCHUNK = LQ * EQ;   // 524288 floats per b-slice of d_out
static constexpr int XO2    = 327680;    // X overlay offset inside each b-slice
// d_out overlay (per b-slice of 524288 floats), phase by phase:
//  stage1 (k_dft2):   Xpart[p][h][m][ri] p=0..3 at b*BCHUNK + p*65536       [0,262144)
//  k_redx:            X[h][m][ri]              at b*BCHUNK + XO2            [327680,393216)
//  stage2 (k_modes3): Opart[hs][c][i] hs=0..3  at b*BCHUNK + (1+hs)*65536   [65536,327680)
//  k_reduce2:         O_final[c][i]            at b*BCHUNK                  [0,65536)
//  stage3 (k_inv2):   y[l][i] overwrites whole slice (reads only own cols of O first)

// ---------------- kernel 0: trig tables ----------------
// T1[l][m][2] = (cos th, -sin th), th = 2*pi*l*m/L       (forward DFT)
// Bas[l][c]:  c=2m   -> ((m==0)?1:2)/L * cos th
//             c=2m+1 -> (m==0)? 0 : -2/L * sin th        (irfft, Im X0 ignored)
__global__ __launch_bounds__(256) void k_trig(float* __restrict__ T1,
                                              float* __restrict__ Bas) {
    int idx = blockIdx.x * 256 + threadIdx.x;   // 0..65535 = l*64+m
    int l = idx >> 6, m = idx & 63;
    int tt = (l * m) & (LQ - 1);
    float ang = (float)tt * 6.135923151542565e-03f;  // 2*pi/1024
    float s, c;
    sincosf(ang, &s, &c);
    T1[idx * 2 + 0] = c;
    T1[idx * 2 + 1] = -s;
    float coef = (m == 0 ? 1.0f : 2.0f) * (1.0f / (float)LQ);
    Bas[l * 128 + 2 * m + 0] = coef * c;
    Bas[l * 128 + 2 * m + 1] = (m == 0) ? 0.0f : (-2.0f / (float)LQ) * s;
}

// ---------------- kernel 1: truncated DFT (l-split x4) ----------------
// Xpart[p][h][m][ri] = sum_{l in p-quarter} q[b][l][h] * (cos, -sin)
// grid 1024 = b(32) x ht(8) x p(4); block 256 = hh(32 h-pairs) x g(8 mode-groups)
__global__ __launch_bounds__(256) void k_dft2(const float* __restrict__ q,
                                              const float* __restrict__ T1,
                                              float* __restrict__ dout) {
    __shared__ float qs[64 * 64];     // [l'][h']  16KB
    __shared__ float ts[64 * 128];    // [l'][m*2+ri] 32KB
    const int t  = threadIdx.x;
    const int blk = blockIdx.x;
    const int b  = blk >> 5;
    const int h0 = ((blk >> 2) & 7) << 6;
    const int p  = blk & 3;
    const int hh = t & 31;            // h-pair index
    const int g  = t >> 5;            // mode group: modes [8g, 8g+8)
    float accr[2][8] = {};
    float acci[2][8] = {};
    const float* qb = q + (size_t)b * (LQ * EQ) + h0;

    for (int lt = 0; lt < 4; ++lt) {
        const int l0 = p * 256 + (lt << 6);
        __syncthreads();
#pragma unroll
        for (int k = 0; k < 16; ++k) {          // stage q tile 64l x 64h
            int idx = k * 256 + t;
            int lp = idx >> 6, hp = idx & 63;
            qs[idx] = qb[(size_t)(l0 + lp) * EQ + hp];
        }
#pragma unroll
        for (int k = 0; k < 32; ++k) {          // stage trig tile 64l x 128
            int idx = k * 256 + t;
            ts[idx] = T1[l0 * 128 + idx];
        }
        __syncthreads();
#pragma unroll 4
        for (int lp = 0; lp < 64; ++lp) {
            float2 qq = *(const float2*)&qs[lp * 64 + 2 * hh];
            const float4* tr = (const float4*)&ts[lp * 128 + g * 16];
#pragma unroll
            for (int j = 0; j < 4; ++j) {       // modes 8g+2j, 8g+2j+1
                float4 tv = tr[j];
                accr[0][2 * j]     += qq.x * tv.x;
                acci[0][2 * j]     += qq.x * tv.y;
                accr[0][2 * j + 1] += qq.x * tv.z;
                acci[0][2 * j + 1] += qq.x * tv.w;
                accr[1][2 * j]     += qq.y * tv.x;
                acci[1][2 * j]     += qq.y * tv.y;
                accr[1][2 * j + 1] += qq.y * tv.z;
                acci[1][2 * j + 1] += qq.y * tv.w;
            }
        }
    }
    float* xb = dout + (size_t)b * BCHUNK + (size_t)p * 65536;
#pragma unroll
    for (int hp = 0; hp < 2; ++hp) {
        int h = h0 + 2 * hh + hp;
#pragma unroll
        for (int mm = 0; mm < 8; ++mm) {
            int m = g * 8 + mm;
            float2 v = make_float2(accr[hp][mm], acci[hp][mm]);
            *(float2*)&xb[(size_t)(h * 64 + m) * 2] = v;
        }
    }
}

// ---------------- kernel 1b: X = sum of 4 l-partials ----------------
__global__ __launch_bounds__(256) void k_redx(float* __restrict__ dout) {
    int idx = blockIdx.x * 256 + threadIdx.x;   // float4 index, 524288 total
    int b = idx >> 14;                          // 16384 float4 per slice-region
    int r = idx & 16383;
    float* base = dout + (size_t)b * BCHUNK;
    float4 s0 = ((const float4*)(base))[r];
    float4 s1 = ((const float4*)(base + 65536))[r];
    float4 s2 = ((const float4*)(base + 2 * 65536))[r];
    float4 s3 = ((const float4*)(base + 3 * 65536))[r];
    float4 o;
    o.x = (s0.x + s1.x) + (s2.x + s3.x);
    o.y = (s0.y + s1.y) + (s2.y + s3.y);
    o.z = (s0.z + s1.z) + (s2.z + s3.z);
    o.w = (s0.w + s1.w) + (s2.w + s3.w);
    ((float4*)(base + XO2))[r] = o;
}

// ---------------- kernel 2: per-mode complex GEMM, v3 (no X staging) ----------------
// Opart[hs][b][2m+ri][i] = sum_{h in hs-range} X[b][h][m] * W[h][i][m]
// grid 256 = hs(4) x it(64, 8 i's). block 512 = m(64 lanes) x slot(8); slot=is(2)xbs(4)
// thread: 4 i's, 8 b's, 1 m. W and X both read straight from global:
// W coalesced over m-lanes (HBM stream, read once); X coalesced, L2-resident (8MB).
// No barriers in main loop -> waves pipeline independently.
__global__ __launch_bounds__(512) void k_modes3(const float* __restrict__ wreal,
                                                const float* __restrict__ wimag,
                                                float* __restrict__ dout) {
    __shared__ float Ot[64 * 66];           // epilogue transpose 16.9KB
    const int t    = threadIdx.x;
    const int m    = t & 63;
    const int slot = t >> 6;
    const int is   = slot & 1;
    const int bs   = slot >> 1;
    const int hs   = blockIdx.x >> 6;
    const int it   = blockIdx.x & 63;
    const int i0   = it * 8;
    const int iTh  = i0 + is * 4;
    // single base pointer; bb strides are compile-time constants
    const char* xbase = (const char*)(dout + (size_t)(bs * 8) * BCHUNK + XO2 + m * 2);
    float ar[4][8] = {}, ai[4][8] = {};

    for (int c = 0; c < 32; ++c) {
        const int h0 = hs * 128 + c * 4;
        // W register prefetch for this 4-h chunk
        float wr[4][4], wim[4][4];
#pragma unroll
        for (int hp = 0; hp < 4; ++hp)
#pragma unroll
            for (int ii = 0; ii < 4; ++ii) {
                size_t g = ((size_t)(h0 + hp) * EQ + (iTh + ii)) * 64 + m;
                wr[hp][ii]  = wreal[g];
                wim[hp][ii] = wimag[g];
            }
#pragma unroll
        for (int hp = 0; hp < 4; ++hp) {
            float2 x[8];
#pragma unroll
            for (int bb = 0; bb < 8; ++bb)
                x[bb] = *(const float2*)(xbase + (size_t)bb * (BCHUNK * 4) +
                                         (size_t)(h0 + hp) * 512);
#pragma unroll
            for (int ii = 0; ii < 4; ++ii) {
                float wrv = wr[hp][ii], wiv = wim[hp][ii];
#pragma unroll
                for (int bb = 0; bb < 8; ++bb) {
                    ar[ii][bb] = fmaf(x[bb].x, wrv, ar[ii][bb]);
                    ar[ii][bb] = fmaf(-x[bb].y, wiv, ar[ii][bb]);
                    ai[ii][bb] = fmaf(x[bb].x, wiv, ai[ii][bb]);
                    ai[ii][bb] = fmaf(x[bb].y, wrv, ai[ii][bb]);
                }
            }
        }
    }
    // epilogue: LDS transpose so stores are 32B-coalesced rows
    for (int bb = 0; bb < 8; ++bb) {
        __syncthreads();
#pragma unroll
        for (int ii = 0; ii < 4; ++ii) {
            float2 v = make_float2(ar[ii][bb], ai[ii][bb]);
            *(float2*)&Ot[m * 66 + (is * 4 + ii) * 8 + bs * 2] = v;
        }
        __syncthreads();
#pragma unroll
        for (int k = 0; k < 8; ++k) {
            int e    = k * 512 + t;          // [bs2(4)][c(128)][iLoc(8)]
            int iLoc = e & 7, cc = (e >> 3) & 127, bs2 = e >> 10;
            float val = Ot[(cc >> 1) * 66 + iLoc * 8 + bs2 * 2 + (cc & 1)];
            int b = bs2 * 8 + bb;
            dout[(size_t)b * BCHUNK + (size_t)(1 + hs) * 65536 +
                 (size_t)cc * EQ + i0 + iLoc] = val;
        }
    }
}

// ---------------- kernel 2b: O_final = sum of 4 h-split partials ----------------
__global__ __launch_bounds__(256) void k_reduce2(float* __restrict__ dout) {
    int idx = blockIdx.x * 256 + threadIdx.x;   // float4 index, 524288 total
    int b = idx >> 14;                          // 16384 float4 per b
    int r = idx & 16383;
    float* base = dout + (size_t)b * BCHUNK;
    float4 s0 = ((const float4*)(base + 65536))[r];
    float4 s1 = ((const float4*)(base + 2 * 65536))[r];
    float4 s2 = ((const float4*)(base + 3 * 65536))[r];
    float4 s3 = ((const float4*)(base + 4 * 65536))[r];
    float4 o;
    o.x = (s0.x + s1.x) + (s2.x + s3.x);
    o.y = (s0.y + s1.y) + (s2.y + s3.y);
    o.z = (s0.z + s1.z) + (s2.z + s3.z);
    o.w = (s0.w + s1.w) + (s2.w + s3.w);
    ((float4*)base)[r] = o;
}

// ---------------- kernel 3: truncated irfft (i-split x16) ----------------
// y[b][l][i] = sum_c Bas[l][c] * O[b][c][i]
// grid 512 = b(32) x it(16: 32 i's); block 256 = lg(32: 2 l's) x ti2(8: 4 i's)
__global__ __launch_bounds__(256) void k_inv2(const float* __restrict__ Bas,
                                              float* __restrict__ dout) {
    __shared__ float Os[128 * 32];    // [c][ii] 16KB — staged BEFORE any write
    __shared__ float Bs[64 * 132];    // [l'][c] padded 33.8KB
    const int t  = threadIdx.x;
    const int b  = blockIdx.x >> 4;
    const int i0 = (blockIdx.x & 15) << 5;
    float* yb = dout + (size_t)b * BCHUNK;
#pragma unroll
    for (int k = 0; k < 16; ++k) {              // stage O (own columns only)
        int e = k * 256 + t;
        int c = e >> 5, ii = e & 31;
        Os[e] = yb[(size_t)c * EQ + i0 + ii];
    }
    __syncthreads();
    const int lg = t >> 3, ti2 = t & 7;
    for (int lt = 0; lt < 16; ++lt) {
        const int l0 = lt << 6;
        if (lt) __syncthreads();
#pragma unroll
        for (int k = 0; k < 32; ++k) {          // stage Bas tile (padded rows)
            int e = k * 256 + t;
            int lp = e >> 7, c = e & 127;
            Bs[lp * 132 + c] = Bas[(size_t)(l0 + lp) * 128 + c];
        }
        __syncthreads();
        float4 acc[2] = {};
#pragma unroll 4
        for (int c = 0; c < 128; ++c) {
            float4 ov = *(const float4*)&Os[c * 32 + ti2 * 4];
#pragma unroll
            for (int j = 0; j < 2; ++j) {
                float bv = Bs[(lg * 2 + j) * 132 + c];
                acc[j].x += bv * ov.x;
                acc[j].y += bv * ov.y;
                acc[j].z += bv * ov.z;
                acc[j].w += bv * ov.w;
            }
        }
#pragma unroll
        for (int j = 0; j < 2; ++j) {
            int l = l0 + lg * 2 + j;
            *(float4*)&yb[(size_t)l * EQ + i0 + ti2 * 4] = acc[j];
        }
    }
}

extern "C" void kernel_launch(void* const* d_in, const int* in_sizes, int n_in,
                              void* d_out, int out_size, void* d_ws, size_t ws_size,
                              hipStream_t stream) {
    const float* q  = (const float*)d_in[0];
    const float* wr = (const float*)d_in[1];
    const float* wi = (const float*)d_in[2];
    float* out = (float*)d_out;
    float* T1  = (float*)d_ws;          // 131072 floats
    float* Bas = T1 + 131072;           // 131072 floats  (1 MB of ws total)

    hipLaunchKernelGGL(k_trig,    dim3(256),  dim3(256), 0, stream, T1, Bas);
    hipLaunchKernelGGL(k_dft2,    dim3(1024), dim3(256), 0, stream, q, T1, out);
    hipLaunchKernelGGL(k_redx,    dim3(2048), dim3(256), 0, stream, out);
    hipLaunchKernelGGL(k_modes3,  dim3(256),  dim3(512), 0, stream, wr, wi, out);
    hipLaunchKernelGGL(k_reduce2, dim3(2048), dim3(256), 0, stream, out);
    hipLaunchKernelGGL(k_inv2,    dim3(512),  dim3(256), 0, stream, Bas, out);
}